// Round 8
// baseline (165.805 us; speedup 1.0000x reference)
//
#include <hip/hip_runtime.h>
#include <stdint.h>

typedef unsigned long long u64;
typedef unsigned int u32;

#define N_PIX (512*512)
#define KW 512
#define KC 2048
#define CAPW 4096
#define CAPC 4096
#define NUM_CLS 68
#define WORD_THR 0.5f
#define CHAR_THR 0.25f
#define IOU_THR 0.3f
#define NBLK 64
#define BS 256
#define GSZ (NBLK*BS)        // 16384 threads; 4 iters of float4 over N_PIX
#define LKCAP 3072           // per-block key stash (4096 px/block, mean 2048, +32 sigma)
#define BASE16W 0x3F00u      // top16 of f32 in (0.5,1)  -> [0x3F00,0x3F80)
#define BASE16C 0x3E80u      // top16 of f32 in (0.25,1) -> [0x3E80,0x3F80)

struct SelState { u64 prefix; u32 kRem; u32 counter; u32 hist[256]; };

// 16-byte aligned: sm.chunk is read via ulonglong2 (ds_read_b128 needs 16B alignment)
union alignas(16) Shm {
  struct { u32 hW[256]; u32 hC[256]; } h;
  u64 chunk[256];
  struct { u64 kw[32]; int changed; } n;
};

__global__ void init_state(SelState* stW, SelState* stC, u32* bars){
  int t = threadIdx.x;
  if (t==0){ stW->prefix=0ull; stW->kRem=KW; stW->counter=0u; }
  if (t==1){ stC->prefix=0ull; stC->kRem=KC; stC->counter=0u; }
  if (t < 8) bars[t] = 0u;
  stW->hist[t]=0u; stC->hist[t]=0u;   // BS==256
}

// 64-lane scan of 256-bin hist (descending): largest digit d with suffix-count >= kRem.
__device__ __forceinline__ void scan_wave(SelState* st, u32 base16, int lane){
  u32 h[4];
  #pragma unroll
  for (int q=0;q<4;q++)
    h[q] = __hip_atomic_load(&st->hist[lane*4+q], __ATOMIC_RELAXED, __HIP_MEMORY_SCOPE_AGENT);
  u32 lsum = h[0]+h[1]+h[2]+h[3];
  u32 v = lsum;
  #pragma unroll
  for (int off=1; off<64; off<<=1){
    u32 t2 = __shfl_down(v, off, 64);
    if (lane + off < 64) v += t2;
  }
  u32 above = v - lsum;                 // sum over lanes > lane
  u32 k = st->kRem;
  u32 sfx1 = h[3]+h[2]+h[1], sfx2 = h[3]+h[2], sfx3 = h[3];
  int best = -1;
  if      (above + sfx3 >= k) best = lane*4+3;
  else if (above + sfx2 >= k) best = lane*4+2;
  else if (above + sfx1 >= k) best = lane*4+1;
  else if (above + lsum >= k) best = lane*4+0;
  u64 m = __ballot(best >= 0);
  int d = 0;
  if (m != 0ull){
    int hi_lane = 63 - __clzll(m);
    d = __shfl(best, hi_lane, 64);
  }
  if (lane==0)
    __hip_atomic_store(&st->prefix, ((u64)(base16 + (u32)d)) << 48,
                       __ATOMIC_RELAXED, __HIP_MEMORY_SCOPE_AGENT);
}

template<int W>
__device__ __forceinline__ void sup_row(int j, int lane, const float4* __restrict__ aabb,
                                        u64* __restrict__ supT, u32* __restrict__ rm){
  float4 bj = aabb[j];
  float aj = fmaxf(bj.z-bj.x,0.0f)*fmaxf(bj.w-bj.y,0.0f);
  u32 m = 0;
  #pragma unroll 4
  for (int w=0; w<W; w++){
    int i = w*64 + lane;
    float4 bi = aabb[i];
    float ai = fmaxf(bi.z-bi.x,0.0f)*fmaxf(bi.w-bi.y,0.0f);
    float ix1=fmaxf(bi.x,bj.x), iy1=fmaxf(bi.y,bj.y);
    float ix2=fminf(bi.z,bj.z), iy2=fminf(bi.w,bj.w);
    float inter = fmaxf(ix2-ix1,0.0f)*fmaxf(iy2-iy1,0.0f);
    float iou = inter/(ai+aj-inter+1e-6f);
    bool bit = (iou > IOU_THR) && (i < j);
    u64 b = __ballot(bit);
    if (b){ if (lane==0) supT[(size_t)j*W + w] = b; m |= 1u << w; }
  }
  if (lane==0) rm[j] = m;
}

template<int K, int W>
__device__ void nms_body(Shm& sm, const u64* __restrict__ supT, const u32* __restrict__ rm,
                         const u64* __restrict__ sorted, float* __restrict__ keep){
  int tid = threadIdx.x;
  int lane = tid & 63, wv = tid >> 6;
  constexpr int NB = K/BS;
  if (tid < W) sm.n.kw[tid] = ~0ull;
  __syncthreads();
  for(;;){
    if (tid==0) sm.n.changed = 0;
    __syncthreads();
    bool nb[NB];
    #pragma unroll
    for (int q=0;q<NB;q++){
      int j = q*BS + tid;
      u32 m = rm[j];
      u64 su = 0ull;
      while (m){ int w = __ffs(m)-1; m &= m-1u; su |= supT[(size_t)j*W + w] & sm.n.kw[w]; }
      nb[q] = (su == 0ull);
    }
    __syncthreads();
    #pragma unroll
    for (int q=0;q<NB;q++){
      u64 b = __ballot(nb[q]);
      if (lane==0){
        int wi = q*(BS/64) + wv;
        if (b != sm.n.kw[wi]){ sm.n.kw[wi] = b; sm.n.changed = 1; }
      }
    }
    __syncthreads();
    int ch = sm.n.changed;
    __syncthreads();
    if (!ch) break;
  }
  #pragma unroll
  for (int q=0;q<NB;q++){
    int j = q*BS + tid;
    u64 key = sorted[j];
    bool pos = ((u32)(key>>32)) != 0u;
    bool kp = (((sm.n.kw[j>>6] >> (j&63)) & 1ull) != 0ull) && pos;
    keep[j] = kp ? 1.0f : 0.0f;
  }
}

__global__ __launch_bounds__(BS)
void mega(const float* __restrict__ wfg, const float* __restrict__ cfg,
          const float* __restrict__ wtblr, const float* __restrict__ worient,
          const float* __restrict__ ctblr, const float* __restrict__ ccls,
          const int* p_sw, const int* p_sh, const int* p_ow, const int* p_oh,
          char* ws, float* out)
{
  // ws layout (phase-overlayed; all accesses < 631824 B)
  u64* candW   = (u64*)(ws + 0);        // dies after P3; then supTW
  u64* candC   = (u64*)(ws + 32768);    // dies after P3; then supTC
  u64* supTW   = (u64*)(ws + 0);
  u64* supTC   = (u64*)(ws + 32768);    // spans to 557056
  u64* sortedW = (u64*)(ws + 557056);
  u64* sortedC = (u64*)(ws + 561152);
  float4* aabbW= (float4*)(ws + 577536);
  float4* aabbC= (float4*)(ws + 585728);
  u32* rmW     = (u32*)(ws + 618496);
  u32* rmC     = (u32*)(ws + 620544);
  SelState* stW= (SelState*)(ws + 628736);
  u32* bars    = (u32*)(ws + 630016);   // 0-2 GBAR, 5 nms-entry, 6 hist-done
  SelState* stC= (SelState*)(ws + 630784);

  float* out_cb = out;                          // char bboxes 2048*9
  float* out_cs = out + KC*9;                   // char scores 2048*68
  float* out_wb = out + KC*9 + KC*NUM_CLS;      // word bboxes 512*9
  float* out_wk = out_wb + KW*9;                // wkeep 512
  float* out_ck = out_wk + KW;                  // ckeep 2048

  __shared__ Shm sm;
  __shared__ u64 lkW[LKCAP];    // this block's passing word keys (4096 px/block)
  __shared__ u64 lkC[LKCAP];
  __shared__ u32 lcW, lcC;
  __shared__ int isLast;
  const int tid = threadIdx.x;
  const int gtid = blockIdx.x*BS + tid;
  const int lane = tid & 63;
  const u64 lmlt = (1ull << lane) - 1ull;
  const float4* wfg4 = (const float4*)wfg;
  const float4* cfg4 = (const float4*)cfg;

  #define GBAR(i) do { __syncthreads(); if (tid==0){                                            \
      __hip_atomic_fetch_add(&bars[i], 1u, __ATOMIC_ACQ_REL, __HIP_MEMORY_SCOPE_AGENT);         \
      while (__hip_atomic_load(&bars[i], __ATOMIC_ACQUIRE, __HIP_MEMORY_SCOPE_AGENT) < (u32)NBLK) \
        __builtin_amdgcn_s_sleep(8);                                                            \
    } __syncthreads(); } while(0)

  // ---------- P0: single top16 hist + LDS key capture ----------
  sm.h.hW[tid] = 0u; sm.h.hC[tid] = 0u;
  if (tid==0){ lcW = 0u; lcC = 0u; }
  __syncthreads();
  for (int g = gtid; g < N_PIX/4; g += GSZ){
    float4 wv4 = wfg4[g];
    float4 cv4 = cfg4[g];
    #pragma unroll
    for (int q=0;q<4;q++){
      float wf = q==0?wv4.x:(q==1?wv4.y:(q==2?wv4.z:wv4.w));
      float cf = q==0?cv4.x:(q==1?cv4.y:(q==2?cv4.z:cv4.w));
      u32 i = 4u*(u32)g + (u32)q;
      bool wp = wf > WORD_THR;
      u64 mW = __ballot(wp);
      if (mW){
        u32 base;
        int ldr = __ffsll(mW) - 1;
        if (lane == ldr) base = atomicAdd(&lcW, (u32)__popcll(mW));
        base = __shfl(base, ldr, 64);
        if (wp){
          u32 fb = __float_as_uint(wf);
          u32 p = base + (u32)__popcll(mW & lmlt);
          if (p < LKCAP) lkW[p] = (((u64)fb)<<32) | (u64)(0xFFFFFFFFu - i);
          atomicAdd(&sm.h.hW[(fb>>16) - BASE16W], 1u);
        }
      }
      bool cp = wp && (cf > CHAR_THR);
      u64 mC = __ballot(cp);
      if (mC){
        u32 base;
        int ldr = __ffsll(mC) - 1;
        if (lane == ldr) base = atomicAdd(&lcC, (u32)__popcll(mC));
        base = __shfl(base, ldr, 64);
        if (cp){
          u32 fb = __float_as_uint(cf);
          u32 p = base + (u32)__popcll(mC & lmlt);
          if (p < LKCAP) lkC[p] = (((u64)fb)<<32) | (u64)(0xFFFFFFFFu - i);
          atomicAdd(&sm.h.hC[(fb>>16) - BASE16C], 1u);
        }
      }
    }
  }
  __syncthreads();
  if (sm.h.hW[tid]) atomicAdd(&stW->hist[tid], sm.h.hW[tid]);
  if (sm.h.hC[tid]) atomicAdd(&stC->hist[tid], sm.h.hC[tid]);
  __syncthreads();
  if (tid==0){
    u32 p = __hip_atomic_fetch_add(&bars[6],1u,__ATOMIC_ACQ_REL,__HIP_MEMORY_SCOPE_AGENT);
    isLast = (p == NBLK-1);
  }
  __syncthreads();
  // ---------- P1: last-done block scans both hists, publishes thresholds ----------
  if (isLast && tid < 128){
    if (tid < 64) scan_wave(stW, BASE16W, lane);
    else          scan_wave(stC, BASE16C, lane);
  }
  GBAR(0);
  // ---------- P2: compact from LDS key lists (no image re-read) ----------
  {
    u64 tW = __hip_atomic_load(&stW->prefix, __ATOMIC_RELAXED, __HIP_MEMORY_SCOPE_AGENT);
    u64 tC = __hip_atomic_load(&stC->prefix, __ATOMIC_RELAXED, __HIP_MEMORY_SCOPE_AGENT);
    u32 nW = min(lcW, (u32)LKCAP), nC = min(lcC, (u32)LKCAP);
    for (u32 t = tid; t < nW; t += BS){
      u64 k = lkW[t];
      if (k >= tW){ u32 p = atomicAdd(&stW->counter,1u); if (p < CAPW) candW[p]=k; }
    }
    for (u32 t = tid; t < nC; t += BS){
      u64 k = lkC[t];
      if (k >= tC){ u32 p = atomicAdd(&stC->counter,1u); if (p < CAPC) candC[p]=k; }
    }
  }
  GBAR(1);
  // ---------- P3: row-group-per-block exact rank + immediate scatter + boxes ----------
  if (blockIdx.x < 32){
    bool isW = (blockIdx.x < 16);
    int sg = isW ? blockIdx.x : blockIdx.x - 16;
    u32 C = isW ? stW->counter : stC->counter;
    u32 cap = isW ? CAPW : CAPC;
    if (C > cap) C = cap;
    int n = (int)((C + 255) >> 8);
    if (sg < n){
      const u64* cand = isW ? candW : candC;
      int slot = sg*256 + tid;
      bool live = slot < (int)C;
      u64 my = live ? cand[slot] : 0ull;
      int rank = 0;
      for (int ch = 0; ch < n; ch++){
        __syncthreads();
        int ci = ch*256 + tid;
        sm.chunk[tid] = (ci < (int)C) ? cand[ci] : 0ull;
        __syncthreads();
        if (live){
          const ulonglong2* cp = (const ulonglong2*)sm.chunk;
          #pragma unroll 8
          for (int i2=0;i2<128;i2++){ ulonglong2 v = cp[i2]; rank += (v.x > my) + (v.y > my); }
        }
      }
      int K = isW ? KW : KC;
      if (live && rank < K){
        (isW ? sortedW : sortedC)[rank] = my;
        u32 idx = 0xFFFFFFFFu - (u32)(my & 0xFFFFFFFFull);
        float score = __uint_as_float((u32)(my>>32));
        float swf = (float)(*p_sw) * 4.0f;    // WORD_STRIDE == CHAR_STRIDE == 4
        float shf = (float)(*p_sh) * 4.0f;
        float owm = (float)(*p_ow) - 1.0f, ohm = (float)(*p_oh) - 1.0f;
        const float* tblr = isW ? wtblr : ctblr;
        float tt2 = tblr[idx], bb = tblr[N_PIX+idx], ll = tblr[2*N_PIX+idx], rr = tblr[3*N_PIX+idx];
        float xf = (float)(idx & 511u), yf = (float)(idx >> 9);
        float c = 1.0f, sn = 0.0f;
        if (isW){ float o = worient[idx]; c = cosf(o); sn = sinf(o); }
        float x1 = swf*(xf - ll), x2 = swf*(xf + rr);
        float y1 = shf*(yf - tt2), y2 = shf*(yf + bb);
        float ax = swf*xf, ay = shf*yf;
        float cx[4] = {x1,x2,x2,x1};
        float cy[4] = {y1,y1,y2,y2};
        float rx[4], ry[4];
        #pragma unroll
        for (int q=0;q<4;q++){
          float dx = cx[q]-ax, dy = cy[q]-ay;
          rx[q] = ax + dx*c - dy*sn;
          ry[q] = ay + dx*sn + dy*c;
        }
        float minx = fminf(fminf(rx[0],rx[1]),fminf(rx[2],rx[3]));
        float maxx = fmaxf(fmaxf(rx[0],rx[1]),fmaxf(rx[2],rx[3]));
        float miny = fminf(fminf(ry[0],ry[1]),fminf(ry[2],ry[3]));
        float maxy = fmaxf(fmaxf(ry[0],ry[1]),fmaxf(ry[2],ry[3]));
        (isW ? aabbW : aabbC)[rank] = make_float4(minx,miny,maxx,maxy);
        float* ob = isW ? out_wb : out_cb;
        #pragma unroll
        for (int q=0;q<4;q++){
          ob[rank*9 + 2*q]   = fminf(fmaxf(rintf(rx[q]),0.0f), owm);
          ob[rank*9 + 2*q+1] = fminf(fmaxf(rintf(ry[q]),0.0f), ohm);
        }
        ob[rank*9+8] = score;
      }
    }
  }
  GBAR(2);
  // ---------- P4: suppression matrix (transposed, sparse rowmask) + class gather ----------
  {
    int gw = gtid >> 6;
    for (int row = gw; row < KW+KC; row += GSZ/64){
      if (row < KW) sup_row<KW/64>(row, lane, aabbW, supTW, rmW);
      else          sup_row<KC/64>(row-KW, lane, aabbC, supTC, rmC);
    }
    for (int t = gtid; t < KC*NUM_CLS; t += GSZ){
      int k = t / NUM_CLS;
      int c = t - k*NUM_CLS;
      u32 idx = 0xFFFFFFFFu - (u32)(sortedC[k] & 0xFFFFFFFFull);
      out_cs[t] = ccls[(size_t)c*N_PIX + idx];
    }
  }
  // ---------- P5: NMS Jacobi fixpoint (blocks 0,1; others arrive & exit) ----------
  __syncthreads();
  if (tid==0) __hip_atomic_fetch_add(&bars[5], 1u, __ATOMIC_ACQ_REL, __HIP_MEMORY_SCOPE_AGENT);
  if (blockIdx.x >= 2) return;
  if (tid==0){
    while (__hip_atomic_load(&bars[5], __ATOMIC_ACQUIRE, __HIP_MEMORY_SCOPE_AGENT) < (u32)NBLK)
      __builtin_amdgcn_s_sleep(8);
  }
  __syncthreads();
  if (blockIdx.x == 0) nms_body<KW, KW/64>(sm, supTW, rmW, sortedW, out_wk);
  else                 nms_body<KC, KC/64>(sm, supTC, rmC, sortedC, out_ck);
  #undef GBAR
}

extern "C" void kernel_launch(void* const* d_in, const int* in_sizes, int n_in,
                              void* d_out, int out_size, void* d_ws, size_t ws_size,
                              hipStream_t stream) {
  const float* wfg     = (const float*)d_in[0];
  const float* wtblr   = (const float*)d_in[1];
  const float* worient = (const float*)d_in[2];
  const float* cfg     = (const float*)d_in[3];
  const float* ctblr   = (const float*)d_in[4];
  const float* ccls    = (const float*)d_in[5];
  const int* p_sw = (const int*)d_in[6];
  const int* p_sh = (const int*)d_in[7];
  const int* p_ow = (const int*)d_in[8];
  const int* p_oh = (const int*)d_in[9];

  char* ws = (char*)d_ws;
  SelState* stW = (SelState*)(ws + 628736);
  u32* bars     = (u32*)(ws + 630016);
  SelState* stC = (SelState*)(ws + 630784);

  init_state<<<1, BS, 0, stream>>>(stW, stC, bars);
  mega<<<NBLK, BS, 0, stream>>>(wfg, cfg, wtblr, worient, ctblr, ccls,
                                p_sw, p_sh, p_ow, p_oh, ws, (float*)d_out);
}

// Round 9
// 138.222 us; speedup vs baseline: 1.1996x; 1.1996x over previous
//
#include <hip/hip_runtime.h>
#include <stdint.h>

typedef unsigned long long u64;
typedef unsigned int u32;

#define N_PIX (512*512)
#define KW 512
#define KC 2048
#define CAPW 4096
#define CAPC 4096
#define NUM_CLS 68
#define WORD_THR 0.5f
#define CHAR_THR 0.25f
#define IOU_THR 0.3f
#define NBLK 128
#define BS 256
#define GSZ (NBLK*BS)        // 32768 threads; 2 iters of float4 over N_PIX; 2048 px/block
#define BASE16W 0x3F00u      // top16 of f32 in (0.5,1)  -> [0x3F00,0x3F80)
#define BASE16C 0x3E80u      // top16 of f32 in (0.25,1) -> [0x3E80,0x3F80)

struct SelState { u64 prefix; u32 kRem; u32 counter; u32 hist[256]; };

// 16-byte aligned: sm.chunk is read via ulonglong2 (ds_read_b128 needs 16B alignment)
union alignas(16) Shm {
  struct { u32 hW[256]; u32 hC[256]; } h;
  u64 chunk[256];
  struct { u64 kw[32]; int changed; } n;
};

__global__ void init_state(SelState* stW, SelState* stC, u32* bars){
  int t = threadIdx.x;
  if (t==0){ stW->prefix=0ull; stW->kRem=KW; stW->counter=0u; }
  if (t==1){ stC->prefix=0ull; stC->kRem=KC; stC->counter=0u; }
  if (t < 8) bars[t] = 0u;
  stW->hist[t]=0u; stC->hist[t]=0u;   // BS==256
}

// 64-lane scan of 256-bin hist (descending): largest digit d with suffix-count >= kRem.
__device__ __forceinline__ void scan_wave(SelState* st, u32 base16, int lane){
  u32 h[4];
  #pragma unroll
  for (int q=0;q<4;q++)
    h[q] = __hip_atomic_load(&st->hist[lane*4+q], __ATOMIC_RELAXED, __HIP_MEMORY_SCOPE_AGENT);
  u32 lsum = h[0]+h[1]+h[2]+h[3];
  u32 v = lsum;
  #pragma unroll
  for (int off=1; off<64; off<<=1){
    u32 t2 = __shfl_down(v, off, 64);
    if (lane + off < 64) v += t2;
  }
  u32 above = v - lsum;                 // sum over lanes > lane
  u32 k = st->kRem;
  u32 sfx1 = h[3]+h[2]+h[1], sfx2 = h[3]+h[2], sfx3 = h[3];
  int best = -1;
  if      (above + sfx3 >= k) best = lane*4+3;
  else if (above + sfx2 >= k) best = lane*4+2;
  else if (above + sfx1 >= k) best = lane*4+1;
  else if (above + lsum >= k) best = lane*4+0;
  u64 m = __ballot(best >= 0);
  int d = 0;
  if (m != 0ull){
    int hi_lane = 63 - __clzll(m);
    d = __shfl(best, hi_lane, 64);
  }
  if (lane==0)
    __hip_atomic_store(&st->prefix, ((u64)(base16 + (u32)d)) << 48,
                       __ATOMIC_RELAXED, __HIP_MEMORY_SCOPE_AGENT);
}

template<int W>
__device__ __forceinline__ void sup_row(int j, int lane, const float4* __restrict__ aabb,
                                        u64* __restrict__ supT, u32* __restrict__ rm){
  float4 bj = aabb[j];
  float aj = fmaxf(bj.z-bj.x,0.0f)*fmaxf(bj.w-bj.y,0.0f);
  u32 m = 0;
  #pragma unroll 4
  for (int w=0; w<W; w++){
    int i = w*64 + lane;
    float4 bi = aabb[i];
    float ai = fmaxf(bi.z-bi.x,0.0f)*fmaxf(bi.w-bi.y,0.0f);
    float ix1=fmaxf(bi.x,bj.x), iy1=fmaxf(bi.y,bj.y);
    float ix2=fminf(bi.z,bj.z), iy2=fminf(bi.w,bj.w);
    float inter = fmaxf(ix2-ix1,0.0f)*fmaxf(iy2-iy1,0.0f);
    float iou = inter/(ai+aj-inter+1e-6f);
    bool bit = (iou > IOU_THR) && (i < j);
    u64 b = __ballot(bit);
    if (b){ if (lane==0) supT[(size_t)j*W + w] = b; m |= 1u << w; }
  }
  if (lane==0) rm[j] = m;
}

template<int K, int W>
__device__ void nms_body(Shm& sm, const u64* __restrict__ supT, const u32* __restrict__ rm,
                         const u64* __restrict__ sorted, float* __restrict__ keep){
  int tid = threadIdx.x;
  int lane = tid & 63, wv = tid >> 6;
  constexpr int NB = K/BS;
  if (tid < W) sm.n.kw[tid] = ~0ull;
  __syncthreads();
  for(;;){
    if (tid==0) sm.n.changed = 0;
    __syncthreads();
    bool nb[NB];
    #pragma unroll
    for (int q=0;q<NB;q++){
      int j = q*BS + tid;
      u32 m = rm[j];
      u64 su = 0ull;
      while (m){ int w = __ffs(m)-1; m &= m-1u; su |= supT[(size_t)j*W + w] & sm.n.kw[w]; }
      nb[q] = (su == 0ull);
    }
    __syncthreads();
    #pragma unroll
    for (int q=0;q<NB;q++){
      u64 b = __ballot(nb[q]);
      if (lane==0){
        int wi = q*(BS/64) + wv;
        if (b != sm.n.kw[wi]){ sm.n.kw[wi] = b; sm.n.changed = 1; }
      }
    }
    __syncthreads();
    int ch = sm.n.changed;
    __syncthreads();
    if (!ch) break;
  }
  #pragma unroll
  for (int q=0;q<NB;q++){
    int j = q*BS + tid;
    u64 key = sorted[j];
    bool pos = ((u32)(key>>32)) != 0u;
    bool kp = (((sm.n.kw[j>>6] >> (j&63)) & 1ull) != 0ull) && pos;
    keep[j] = kp ? 1.0f : 0.0f;
  }
}

__global__ __launch_bounds__(BS)
void mega(const float* __restrict__ wfg, const float* __restrict__ cfg,
          const float* __restrict__ wtblr, const float* __restrict__ worient,
          const float* __restrict__ ctblr, const float* __restrict__ ccls,
          const int* p_sw, const int* p_sh, const int* p_ow, const int* p_oh,
          char* ws, float* out)
{
  // ws layout (phase-overlayed; all accesses < 631824 B)
  u64* candW   = (u64*)(ws + 0);        // dies after P3; then supTW
  u64* candC   = (u64*)(ws + 32768);    // dies after P3; then supTC
  u64* supTW   = (u64*)(ws + 0);
  u64* supTC   = (u64*)(ws + 32768);    // spans to 557056
  u64* sortedW = (u64*)(ws + 557056);
  u64* sortedC = (u64*)(ws + 561152);
  float4* aabbW= (float4*)(ws + 577536);
  float4* aabbC= (float4*)(ws + 585728);
  u32* rmW     = (u32*)(ws + 618496);
  u32* rmC     = (u32*)(ws + 620544);
  SelState* stW= (SelState*)(ws + 628736);
  u32* bars    = (u32*)(ws + 630016);   // 0 scan-release, 1,2 GBAR, 5 nms-entry
  SelState* stC= (SelState*)(ws + 630784);

  float* out_cb = out;                          // char bboxes 2048*9
  float* out_cs = out + KC*9;                   // char scores 2048*68
  float* out_wb = out + KC*9 + KC*NUM_CLS;      // word bboxes 512*9
  float* out_wk = out_wb + KW*9;                // wkeep 512
  float* out_ck = out_wk + KW;                  // ckeep 2048

  __shared__ Shm sm;
  __shared__ u64 lkW[2048];     // this block's passing word keys (2048 px/block max)
  __shared__ u64 lkC[2048];
  __shared__ u32 lcW, lcC;
  __shared__ int isLast;
  const int tid = threadIdx.x;
  const int gtid = blockIdx.x*BS + tid;
  const int lane = tid & 63;
  const u64 lmlt = (1ull << lane) - 1ull;
  const float4* wfg4 = (const float4*)wfg;
  const float4* cfg4 = (const float4*)cfg;

  #define GBAR(i) do { __syncthreads(); if (tid==0){                                            \
      __hip_atomic_fetch_add(&bars[i], 1u, __ATOMIC_ACQ_REL, __HIP_MEMORY_SCOPE_AGENT);         \
      while (__hip_atomic_load(&bars[i], __ATOMIC_ACQUIRE, __HIP_MEMORY_SCOPE_AGENT) < (u32)NBLK) \
        __builtin_amdgcn_s_sleep(8);                                                            \
    } __syncthreads(); } while(0)

  // ---------- P0: single top16 hist + LDS key capture ----------
  sm.h.hW[tid] = 0u; sm.h.hC[tid] = 0u;
  if (tid==0){ lcW = 0u; lcC = 0u; }
  __syncthreads();
  for (int g = gtid; g < N_PIX/4; g += GSZ){
    float4 wv4 = wfg4[g];
    float4 cv4 = cfg4[g];
    #pragma unroll
    for (int q=0;q<4;q++){
      float wf = q==0?wv4.x:(q==1?wv4.y:(q==2?wv4.z:wv4.w));
      float cf = q==0?cv4.x:(q==1?cv4.y:(q==2?cv4.z:cv4.w));
      u32 i = 4u*(u32)g + (u32)q;
      bool wp = wf > WORD_THR;
      u64 mW = __ballot(wp);
      if (mW){
        u32 base;
        int ldr = __ffsll(mW) - 1;
        if (lane == ldr) base = atomicAdd(&lcW, (u32)__popcll(mW));
        base = __shfl(base, ldr, 64);
        if (wp){
          u32 fb = __float_as_uint(wf);
          lkW[base + (u32)__popcll(mW & lmlt)] = (((u64)fb)<<32) | (u64)(0xFFFFFFFFu - i);
          atomicAdd(&sm.h.hW[(fb>>16) - BASE16W], 1u);
        }
      }
      bool cp = wp && (cf > CHAR_THR);
      u64 mC = __ballot(cp);
      if (mC){
        u32 base;
        int ldr = __ffsll(mC) - 1;
        if (lane == ldr) base = atomicAdd(&lcC, (u32)__popcll(mC));
        base = __shfl(base, ldr, 64);
        if (cp){
          u32 fb = __float_as_uint(cf);
          lkC[base + (u32)__popcll(mC & lmlt)] = (((u64)fb)<<32) | (u64)(0xFFFFFFFFu - i);
          atomicAdd(&sm.h.hC[(fb>>16) - BASE16C], 1u);
        }
      }
    }
  }
  __syncthreads();
  if (sm.h.hW[tid]) atomicAdd(&stW->hist[tid], sm.h.hW[tid]);
  if (sm.h.hC[tid]) atomicAdd(&stC->hist[tid], sm.h.hC[tid]);
  // ---------- P1: merged barrier -- last arriver scans, releases sentinel ----------
  __syncthreads();
  if (tid==0){
    u32 p = __hip_atomic_fetch_add(&bars[0],1u,__ATOMIC_ACQ_REL,__HIP_MEMORY_SCOPE_AGENT);
    isLast = (p == NBLK-1);
  }
  __syncthreads();
  if (isLast){
    if (tid < 128){
      if (tid < 64) scan_wave(stW, BASE16W, lane);
      else          scan_wave(stC, BASE16C, lane);
    }
    __syncthreads();
    if (tid==0)
      __hip_atomic_store(&bars[0], 0xFFFFFFFFu, __ATOMIC_RELEASE, __HIP_MEMORY_SCOPE_AGENT);
  } else if (tid==0){
    while (__hip_atomic_load(&bars[0], __ATOMIC_ACQUIRE, __HIP_MEMORY_SCOPE_AGENT) != 0xFFFFFFFFu)
      __builtin_amdgcn_s_sleep(8);
  }
  __syncthreads();
  // ---------- P2: compact from LDS key lists (no image re-read) ----------
  {
    u64 tW = __hip_atomic_load(&stW->prefix, __ATOMIC_RELAXED, __HIP_MEMORY_SCOPE_AGENT);
    u64 tC = __hip_atomic_load(&stC->prefix, __ATOMIC_RELAXED, __HIP_MEMORY_SCOPE_AGENT);
    u32 nW = lcW, nC = lcC;
    for (u32 t = tid; t < nW; t += BS){
      u64 k = lkW[t];
      if (k >= tW){ u32 p = atomicAdd(&stW->counter,1u); if (p < CAPW) candW[p]=k; }
    }
    for (u32 t = tid; t < nC; t += BS){
      u64 k = lkC[t];
      if (k >= tC){ u32 p = atomicAdd(&stC->counter,1u); if (p < CAPC) candC[p]=k; }
    }
  }
  GBAR(1);
  // ---------- P3: row-group-per-block exact rank + immediate scatter + boxes ----------
  if (blockIdx.x < 32){
    bool isW = (blockIdx.x < 16);
    int sg = isW ? blockIdx.x : blockIdx.x - 16;
    u32 C = isW ? stW->counter : stC->counter;
    u32 cap = isW ? CAPW : CAPC;
    if (C > cap) C = cap;
    int n = (int)((C + 255) >> 8);
    if (sg < n){
      const u64* cand = isW ? candW : candC;
      int slot = sg*256 + tid;
      bool live = slot < (int)C;
      u64 my = live ? cand[slot] : 0ull;
      int rank = 0;
      for (int ch = 0; ch < n; ch++){
        __syncthreads();
        int ci = ch*256 + tid;
        sm.chunk[tid] = (ci < (int)C) ? cand[ci] : 0ull;
        __syncthreads();
        if (live){
          const ulonglong2* cp = (const ulonglong2*)sm.chunk;
          #pragma unroll 8
          for (int i2=0;i2<128;i2++){ ulonglong2 v = cp[i2]; rank += (v.x > my) + (v.y > my); }
        }
      }
      int K = isW ? KW : KC;
      if (live && rank < K){
        (isW ? sortedW : sortedC)[rank] = my;
        u32 idx = 0xFFFFFFFFu - (u32)(my & 0xFFFFFFFFull);
        float score = __uint_as_float((u32)(my>>32));
        float swf = (float)(*p_sw) * 4.0f;    // WORD_STRIDE == CHAR_STRIDE == 4
        float shf = (float)(*p_sh) * 4.0f;
        float owm = (float)(*p_ow) - 1.0f, ohm = (float)(*p_oh) - 1.0f;
        const float* tblr = isW ? wtblr : ctblr;
        float tt2 = tblr[idx], bb = tblr[N_PIX+idx], ll = tblr[2*N_PIX+idx], rr = tblr[3*N_PIX+idx];
        float xf = (float)(idx & 511u), yf = (float)(idx >> 9);
        float c = 1.0f, sn = 0.0f;
        if (isW){ float o = worient[idx]; c = cosf(o); sn = sinf(o); }
        float x1 = swf*(xf - ll), x2 = swf*(xf + rr);
        float y1 = shf*(yf - tt2), y2 = shf*(yf + bb);
        float ax = swf*xf, ay = shf*yf;
        float cx[4] = {x1,x2,x2,x1};
        float cy[4] = {y1,y1,y2,y2};
        float rx[4], ry[4];
        #pragma unroll
        for (int q=0;q<4;q++){
          float dx = cx[q]-ax, dy = cy[q]-ay;
          rx[q] = ax + dx*c - dy*sn;
          ry[q] = ay + dx*sn + dy*c;
        }
        float minx = fminf(fminf(rx[0],rx[1]),fminf(rx[2],rx[3]));
        float maxx = fmaxf(fmaxf(rx[0],rx[1]),fmaxf(rx[2],rx[3]));
        float miny = fminf(fminf(ry[0],ry[1]),fminf(ry[2],ry[3]));
        float maxy = fmaxf(fmaxf(ry[0],ry[1]),fmaxf(ry[2],ry[3]));
        (isW ? aabbW : aabbC)[rank] = make_float4(minx,miny,maxx,maxy);
        float* ob = isW ? out_wb : out_cb;
        #pragma unroll
        for (int q=0;q<4;q++){
          ob[rank*9 + 2*q]   = fminf(fmaxf(rintf(rx[q]),0.0f), owm);
          ob[rank*9 + 2*q+1] = fminf(fmaxf(rintf(ry[q]),0.0f), ohm);
        }
        ob[rank*9+8] = score;
      }
    }
  }
  GBAR(2);
  // ---------- P4: suppression matrix (transposed, sparse rowmask) ----------
  {
    int gw = gtid >> 6;                        // 512 waves, 5 rows each
    for (int row = gw; row < KW+KC; row += GSZ/64){
      if (row < KW) sup_row<KW/64>(row, lane, aabbW, supTW, rmW);
      else          sup_row<KC/64>(row-KW, lane, aabbC, supTC, rmC);
    }
  }
  // ---------- P5: NMS entry; blocks >=2 gather classes off critical path ----------
  __syncthreads();
  if (tid==0) __hip_atomic_fetch_add(&bars[5], 1u, __ATOMIC_ACQ_REL, __HIP_MEMORY_SCOPE_AGENT);
  if (blockIdx.x >= 2){
    // class gather overlaps NMS on blocks 0/1 (reads sortedC, protected by GBAR(2))
    for (int t = (blockIdx.x-2)*BS + tid; t < KC*NUM_CLS; t += (NBLK-2)*BS){
      int k = t / NUM_CLS;
      int c = t - k*NUM_CLS;
      u32 idx = 0xFFFFFFFFu - (u32)(sortedC[k] & 0xFFFFFFFFull);
      out_cs[t] = ccls[(size_t)c*N_PIX + idx];
    }
    return;
  }
  if (tid==0){
    while (__hip_atomic_load(&bars[5], __ATOMIC_ACQUIRE, __HIP_MEMORY_SCOPE_AGENT) < (u32)NBLK)
      __builtin_amdgcn_s_sleep(8);
  }
  __syncthreads();
  if (blockIdx.x == 0) nms_body<KW, KW/64>(sm, supTW, rmW, sortedW, out_wk);
  else                 nms_body<KC, KC/64>(sm, supTC, rmC, sortedC, out_ck);
  #undef GBAR
}

extern "C" void kernel_launch(void* const* d_in, const int* in_sizes, int n_in,
                              void* d_out, int out_size, void* d_ws, size_t ws_size,
                              hipStream_t stream) {
  const float* wfg     = (const float*)d_in[0];
  const float* wtblr   = (const float*)d_in[1];
  const float* worient = (const float*)d_in[2];
  const float* cfg     = (const float*)d_in[3];
  const float* ctblr   = (const float*)d_in[4];
  const float* ccls    = (const float*)d_in[5];
  const int* p_sw = (const int*)d_in[6];
  const int* p_sh = (const int*)d_in[7];
  const int* p_ow = (const int*)d_in[8];
  const int* p_oh = (const int*)d_in[9];

  char* ws = (char*)d_ws;
  SelState* stW = (SelState*)(ws + 628736);
  u32* bars     = (u32*)(ws + 630016);
  SelState* stC = (SelState*)(ws + 630784);

  init_state<<<1, BS, 0, stream>>>(stW, stC, bars);
  mega<<<NBLK, BS, 0, stream>>>(wfg, cfg, wtblr, worient, ctblr, ccls,
                                p_sw, p_sh, p_ow, p_oh, ws, (float*)d_out);
}

// Round 10
// 123.708 us; speedup vs baseline: 1.3403x; 1.1173x over previous
//
#include <hip/hip_runtime.h>
#include <stdint.h>

typedef unsigned long long u64;
typedef unsigned int u32;

#define N_PIX (512*512)
#define KW 512
#define KC 2048
#define CAPW 4096
#define CAPC 4096
#define NUM_CLS 68
#define WORD_THR 0.5f
#define CHAR_THR 0.25f
#define IOU_THR 0.3f
#define NBLK 128
#define BS 512
#define GSZ (NBLK*BS)        // 65536 threads; exactly N_PIX/4 float4s; 2048 px/block
#define BASE16W 0x3F00u      // top16 of f32 in (0.5,1)  -> [0x3F00,0x3F80)
#define BASE16C 0x3E80u      // top16 of f32 in (0.25,1) -> [0x3E80,0x3F80)

struct SelState { u64 prefix; u32 kRem; u32 counter; u32 hist[256]; };

// 16-byte aligned: sm.chunk is read via ulonglong2 (ds_read_b128 needs 16B alignment)
union alignas(16) Shm {
  struct { u32 hW[256]; u32 hC[256]; } h;
  u64 chunk[BS];                       // 512-key rank chunk (4 KB)
  struct { u64 kw[32]; int changed; } n;
};

__global__ void init_state(SelState* stW, SelState* stC, u32* bars){
  int t = threadIdx.x;
  if (t==0){ stW->prefix=0ull; stW->kRem=KW; stW->counter=0u; }
  if (t==1){ stC->prefix=0ull; stC->kRem=KC; stC->counter=0u; }
  if (t < 8) bars[t] = 0u;
  if (t < 256){ stW->hist[t]=0u; stC->hist[t]=0u; }
}

// 64-lane scan of 256-bin hist (descending): largest digit d with suffix-count >= kRem.
__device__ __forceinline__ void scan_wave(SelState* st, u32 base16, int lane){
  u32 h[4];
  #pragma unroll
  for (int q=0;q<4;q++)
    h[q] = __hip_atomic_load(&st->hist[lane*4+q], __ATOMIC_RELAXED, __HIP_MEMORY_SCOPE_AGENT);
  u32 lsum = h[0]+h[1]+h[2]+h[3];
  u32 v = lsum;
  #pragma unroll
  for (int off=1; off<64; off<<=1){
    u32 t2 = __shfl_down(v, off, 64);
    if (lane + off < 64) v += t2;
  }
  u32 above = v - lsum;                 // sum over lanes > lane
  u32 k = st->kRem;
  u32 sfx1 = h[3]+h[2]+h[1], sfx2 = h[3]+h[2], sfx3 = h[3];
  int best = -1;
  if      (above + sfx3 >= k) best = lane*4+3;
  else if (above + sfx2 >= k) best = lane*4+2;
  else if (above + sfx1 >= k) best = lane*4+1;
  else if (above + lsum >= k) best = lane*4+0;
  u64 m = __ballot(best >= 0);
  int d = 0;
  if (m != 0ull){
    int hi_lane = 63 - __clzll(m);
    d = __shfl(best, hi_lane, 64);
  }
  if (lane==0)
    __hip_atomic_store(&st->prefix, ((u64)(base16 + (u32)d)) << 48,
                       __ATOMIC_RELAXED, __HIP_MEMORY_SCOPE_AGENT);
}

template<int W>
__device__ __forceinline__ void sup_row(int j, int lane, const float4* __restrict__ aabb,
                                        u64* __restrict__ supT, u32* __restrict__ rm){
  float4 bj = aabb[j];
  float aj = fmaxf(bj.z-bj.x,0.0f)*fmaxf(bj.w-bj.y,0.0f);
  u32 m = 0;
  #pragma unroll 4
  for (int w=0; w<W; w++){
    int i = w*64 + lane;
    float4 bi = aabb[i];
    float ai = fmaxf(bi.z-bi.x,0.0f)*fmaxf(bi.w-bi.y,0.0f);
    float ix1=fmaxf(bi.x,bj.x), iy1=fmaxf(bi.y,bj.y);
    float ix2=fminf(bi.z,bj.z), iy2=fminf(bi.w,bj.w);
    float inter = fmaxf(ix2-ix1,0.0f)*fmaxf(iy2-iy1,0.0f);
    float iou = inter/(ai+aj-inter+1e-6f);
    bool bit = (iou > IOU_THR) && (i < j);
    u64 b = __ballot(bit);
    if (b){ if (lane==0) supT[(size_t)j*W + w] = b; m |= 1u << w; }
  }
  if (lane==0) rm[j] = m;
}

template<int K, int W>
__device__ void nms_body(Shm& sm, const u64* __restrict__ supT, const u32* __restrict__ rm,
                         const u64* __restrict__ sorted, float* __restrict__ keep){
  int tid = threadIdx.x;
  int lane = tid & 63, wv = tid >> 6;
  constexpr int NB = (K + BS - 1)/BS;
  if (tid < W) sm.n.kw[tid] = ~0ull;
  __syncthreads();
  for(;;){
    if (tid==0) sm.n.changed = 0;
    __syncthreads();
    bool nb[NB];
    #pragma unroll
    for (int q=0;q<NB;q++){
      int j = q*BS + tid;
      bool ok = (j < K);
      u64 su = 0ull;
      if (ok){
        u32 m = rm[j];
        while (m){ int w = __ffs(m)-1; m &= m-1u; su |= supT[(size_t)j*W + w] & sm.n.kw[w]; }
      }
      nb[q] = ok && (su == 0ull);
    }
    __syncthreads();
    #pragma unroll
    for (int q=0;q<NB;q++){
      int wi = q*(BS/64) + wv;
      u64 b = __ballot(nb[q]);
      if (lane==0 && wi < W){
        if (b != sm.n.kw[wi]){ sm.n.kw[wi] = b; sm.n.changed = 1; }
      }
    }
    __syncthreads();
    int ch = sm.n.changed;
    __syncthreads();
    if (!ch) break;
  }
  #pragma unroll
  for (int q=0;q<NB;q++){
    int j = q*BS + tid;
    if (j < K){
      u64 key = sorted[j];
      bool pos = ((u32)(key>>32)) != 0u;
      bool kp = (((sm.n.kw[j>>6] >> (j&63)) & 1ull) != 0ull) && pos;
      keep[j] = kp ? 1.0f : 0.0f;
    }
  }
}

__global__ __launch_bounds__(BS)
void mega(const float* __restrict__ wfg, const float* __restrict__ cfg,
          const float* __restrict__ wtblr, const float* __restrict__ worient,
          const float* __restrict__ ctblr, const float* __restrict__ ccls,
          const int* p_sw, const int* p_sh, const int* p_ow, const int* p_oh,
          char* ws, float* out)
{
  // ws layout (phase-overlayed; all accesses < 631824 B)
  u64* candW   = (u64*)(ws + 0);        // dies after P3; then supTW
  u64* candC   = (u64*)(ws + 32768);    // dies after P3; then supTC
  u64* supTW   = (u64*)(ws + 0);
  u64* supTC   = (u64*)(ws + 32768);    // spans to 557056
  u64* sortedW = (u64*)(ws + 557056);
  u64* sortedC = (u64*)(ws + 561152);
  float4* aabbW= (float4*)(ws + 577536);
  float4* aabbC= (float4*)(ws + 585728);
  u32* rmW     = (u32*)(ws + 618496);
  u32* rmC     = (u32*)(ws + 620544);
  SelState* stW= (SelState*)(ws + 628736);
  u32* bars    = (u32*)(ws + 630016);   // 0 scan-release, 1,2 GBAR, 5 nms-entry
  SelState* stC= (SelState*)(ws + 630784);

  float* out_cb = out;                          // char bboxes 2048*9
  float* out_cs = out + KC*9;                   // char scores 2048*68
  float* out_wb = out + KC*9 + KC*NUM_CLS;      // word bboxes 512*9
  float* out_wk = out_wb + KW*9;                // wkeep 512
  float* out_ck = out_wk + KW;                  // ckeep 2048

  __shared__ Shm sm;
  __shared__ u64 lkW[2048];     // this block's passing word keys (2048 px/block max)
  __shared__ u64 lkC[2048];
  __shared__ u32 lcW, lcC;
  __shared__ int isLast;
  const int tid = threadIdx.x;
  const int gtid = blockIdx.x*BS + tid;
  const int lane = tid & 63;
  const u64 lmlt = (1ull << lane) - 1ull;
  const float4* wfg4 = (const float4*)wfg;
  const float4* cfg4 = (const float4*)cfg;

  #define GBAR(i) do { __syncthreads(); if (tid==0){                                            \
      __hip_atomic_fetch_add(&bars[i], 1u, __ATOMIC_ACQ_REL, __HIP_MEMORY_SCOPE_AGENT);         \
      while (__hip_atomic_load(&bars[i], __ATOMIC_ACQUIRE, __HIP_MEMORY_SCOPE_AGENT) < (u32)NBLK) \
        __builtin_amdgcn_s_sleep(8);                                                            \
    } __syncthreads(); } while(0)

  // ---------- P0: single top16 hist + LDS key capture (1 iter: GSZ==N_PIX/4) ----------
  if (tid < 256){ sm.h.hW[tid] = 0u; sm.h.hC[tid] = 0u; }
  if (tid==0){ lcW = 0u; lcC = 0u; }
  __syncthreads();
  {
    float4 wv4 = wfg4[gtid];
    float4 cv4 = cfg4[gtid];
    #pragma unroll
    for (int q=0;q<4;q++){
      float wf = q==0?wv4.x:(q==1?wv4.y:(q==2?wv4.z:wv4.w));
      float cf = q==0?cv4.x:(q==1?cv4.y:(q==2?cv4.z:cv4.w));
      u32 i = 4u*(u32)gtid + (u32)q;
      bool wp = wf > WORD_THR;
      u64 mW = __ballot(wp);
      if (mW){
        u32 base;
        int ldr = __ffsll(mW) - 1;
        if (lane == ldr) base = atomicAdd(&lcW, (u32)__popcll(mW));
        base = __shfl(base, ldr, 64);
        if (wp){
          u32 fb = __float_as_uint(wf);
          lkW[base + (u32)__popcll(mW & lmlt)] = (((u64)fb)<<32) | (u64)(0xFFFFFFFFu - i);
          atomicAdd(&sm.h.hW[(fb>>16) - BASE16W], 1u);
        }
      }
      bool cp = wp && (cf > CHAR_THR);
      u64 mC = __ballot(cp);
      if (mC){
        u32 base;
        int ldr = __ffsll(mC) - 1;
        if (lane == ldr) base = atomicAdd(&lcC, (u32)__popcll(mC));
        base = __shfl(base, ldr, 64);
        if (cp){
          u32 fb = __float_as_uint(cf);
          lkC[base + (u32)__popcll(mC & lmlt)] = (((u64)fb)<<32) | (u64)(0xFFFFFFFFu - i);
          atomicAdd(&sm.h.hC[(fb>>16) - BASE16C], 1u);
        }
      }
    }
  }
  __syncthreads();
  if (tid < 256){
    if (sm.h.hW[tid]) atomicAdd(&stW->hist[tid], sm.h.hW[tid]);
    if (sm.h.hC[tid]) atomicAdd(&stC->hist[tid], sm.h.hC[tid]);
  }
  // ---------- P1: merged barrier -- last arriver scans, releases sentinel ----------
  __syncthreads();
  if (tid==0){
    u32 p = __hip_atomic_fetch_add(&bars[0],1u,__ATOMIC_ACQ_REL,__HIP_MEMORY_SCOPE_AGENT);
    isLast = (p == NBLK-1);
  }
  __syncthreads();
  if (isLast){
    if (tid < 128){
      if (tid < 64) scan_wave(stW, BASE16W, lane);
      else          scan_wave(stC, BASE16C, lane);
    }
    __syncthreads();
    if (tid==0)
      __hip_atomic_store(&bars[0], 0xFFFFFFFFu, __ATOMIC_RELEASE, __HIP_MEMORY_SCOPE_AGENT);
  } else if (tid==0){
    while (__hip_atomic_load(&bars[0], __ATOMIC_ACQUIRE, __HIP_MEMORY_SCOPE_AGENT) != 0xFFFFFFFFu)
      __builtin_amdgcn_s_sleep(8);
  }
  __syncthreads();
  // ---------- P2: compact from LDS key lists (no image re-read) ----------
  {
    u64 tW = __hip_atomic_load(&stW->prefix, __ATOMIC_RELAXED, __HIP_MEMORY_SCOPE_AGENT);
    u64 tC = __hip_atomic_load(&stC->prefix, __ATOMIC_RELAXED, __HIP_MEMORY_SCOPE_AGENT);
    u32 nW = lcW, nC = lcC;
    for (u32 t = tid; t < nW; t += BS){
      u64 k = lkW[t];
      if (k >= tW){ u32 p = atomicAdd(&stW->counter,1u); if (p < CAPW) candW[p]=k; }
    }
    for (u32 t = tid; t < nC; t += BS){
      u64 k = lkC[t];
      if (k >= tC){ u32 p = atomicAdd(&stC->counter,1u); if (p < CAPC) candC[p]=k; }
    }
  }
  GBAR(1);
  // ---------- P3: row-group-per-block exact rank + immediate scatter + boxes ----------
  if (blockIdx.x < 16){
    bool isW = (blockIdx.x < 8);
    int sg = isW ? blockIdx.x : blockIdx.x - 8;
    u32 C = isW ? stW->counter : stC->counter;
    u32 cap = isW ? CAPW : CAPC;
    if (C > cap) C = cap;
    int n = (int)((C + BS - 1) / BS);
    if (sg < n){
      const u64* cand = isW ? candW : candC;
      int slot = sg*BS + tid;
      bool live = slot < (int)C;
      u64 my = live ? cand[slot] : 0ull;
      int rank = 0;
      for (int ch = 0; ch < n; ch++){
        __syncthreads();
        int ci = ch*BS + tid;
        sm.chunk[tid] = (ci < (int)C) ? cand[ci] : 0ull;
        __syncthreads();
        if (live){
          const ulonglong2* cp = (const ulonglong2*)sm.chunk;
          #pragma unroll 8
          for (int i2=0;i2<BS/2;i2++){ ulonglong2 v = cp[i2]; rank += (v.x > my) + (v.y > my); }
        }
      }
      int K = isW ? KW : KC;
      if (live && rank < K){
        (isW ? sortedW : sortedC)[rank] = my;
        u32 idx = 0xFFFFFFFFu - (u32)(my & 0xFFFFFFFFull);
        float score = __uint_as_float((u32)(my>>32));
        float swf = (float)(*p_sw) * 4.0f;    // WORD_STRIDE == CHAR_STRIDE == 4
        float shf = (float)(*p_sh) * 4.0f;
        float owm = (float)(*p_ow) - 1.0f, ohm = (float)(*p_oh) - 1.0f;
        const float* tblr = isW ? wtblr : ctblr;
        float tt2 = tblr[idx], bb = tblr[N_PIX+idx], ll = tblr[2*N_PIX+idx], rr = tblr[3*N_PIX+idx];
        float xf = (float)(idx & 511u), yf = (float)(idx >> 9);
        float c = 1.0f, sn = 0.0f;
        if (isW){ float o = worient[idx]; c = cosf(o); sn = sinf(o); }
        float x1 = swf*(xf - ll), x2 = swf*(xf + rr);
        float y1 = shf*(yf - tt2), y2 = shf*(yf + bb);
        float ax = swf*xf, ay = shf*yf;
        float cx[4] = {x1,x2,x2,x1};
        float cy[4] = {y1,y1,y2,y2};
        float rx[4], ry[4];
        #pragma unroll
        for (int q=0;q<4;q++){
          float dx = cx[q]-ax, dy = cy[q]-ay;
          rx[q] = ax + dx*c - dy*sn;
          ry[q] = ay + dx*sn + dy*c;
        }
        float minx = fminf(fminf(rx[0],rx[1]),fminf(rx[2],rx[3]));
        float maxx = fmaxf(fmaxf(rx[0],rx[1]),fmaxf(rx[2],rx[3]));
        float miny = fminf(fminf(ry[0],ry[1]),fminf(ry[2],ry[3]));
        float maxy = fmaxf(fmaxf(ry[0],ry[1]),fmaxf(ry[2],ry[3]));
        (isW ? aabbW : aabbC)[rank] = make_float4(minx,miny,maxx,maxy);
        float* ob = isW ? out_wb : out_cb;
        #pragma unroll
        for (int q=0;q<4;q++){
          ob[rank*9 + 2*q]   = fminf(fmaxf(rintf(rx[q]),0.0f), owm);
          ob[rank*9 + 2*q+1] = fminf(fmaxf(rintf(ry[q]),0.0f), ohm);
        }
        ob[rank*9+8] = score;
      }
    }
  }
  GBAR(2);
  // ---------- P4: suppression matrix (transposed, sparse rowmask) + class gather ----------
  {
    int gw = gtid >> 6;                        // 1024 waves, 2-3 rows each
    for (int row = gw; row < KW+KC; row += GSZ/64){
      if (row < KW) sup_row<KW/64>(row, lane, aabbW, supTW, rmW);
      else          sup_row<KC/64>(row-KW, lane, aabbC, supTC, rmC);
    }
    for (int t = gtid; t < KC*NUM_CLS; t += GSZ){
      int k = t / NUM_CLS;
      int c = t - k*NUM_CLS;
      u32 idx = 0xFFFFFFFFu - (u32)(sortedC[k] & 0xFFFFFFFFull);
      out_cs[t] = ccls[(size_t)c*N_PIX + idx];
    }
  }
  // ---------- P5: NMS Jacobi fixpoint (blocks 0,1; others arrive & exit) ----------
  __syncthreads();
  if (tid==0) __hip_atomic_fetch_add(&bars[5], 1u, __ATOMIC_ACQ_REL, __HIP_MEMORY_SCOPE_AGENT);
  if (blockIdx.x >= 2) return;
  if (tid==0){
    while (__hip_atomic_load(&bars[5], __ATOMIC_ACQUIRE, __HIP_MEMORY_SCOPE_AGENT) < (u32)NBLK)
      __builtin_amdgcn_s_sleep(8);
  }
  __syncthreads();
  if (blockIdx.x == 0) nms_body<KW, KW/64>(sm, supTW, rmW, sortedW, out_wk);
  else                 nms_body<KC, KC/64>(sm, supTC, rmC, sortedC, out_ck);
  #undef GBAR
}

extern "C" void kernel_launch(void* const* d_in, const int* in_sizes, int n_in,
                              void* d_out, int out_size, void* d_ws, size_t ws_size,
                              hipStream_t stream) {
  const float* wfg     = (const float*)d_in[0];
  const float* wtblr   = (const float*)d_in[1];
  const float* worient = (const float*)d_in[2];
  const float* cfg     = (const float*)d_in[3];
  const float* ctblr   = (const float*)d_in[4];
  const float* ccls    = (const float*)d_in[5];
  const int* p_sw = (const int*)d_in[6];
  const int* p_sh = (const int*)d_in[7];
  const int* p_ow = (const int*)d_in[8];
  const int* p_oh = (const int*)d_in[9];

  char* ws = (char*)d_ws;
  SelState* stW = (SelState*)(ws + 628736);
  u32* bars     = (u32*)(ws + 630016);
  SelState* stC = (SelState*)(ws + 630784);

  init_state<<<1, BS, 0, stream>>>(stW, stC, bars);
  mega<<<NBLK, BS, 0, stream>>>(wfg, cfg, wtblr, worient, ctblr, ccls,
                                p_sw, p_sh, p_ow, p_oh, ws, (float*)d_out);
}

// Round 11
// 103.003 us; speedup vs baseline: 1.6097x; 1.2010x over previous
//
#include <hip/hip_runtime.h>
#include <stdint.h>

typedef unsigned long long u64;
typedef unsigned int u32;

#define N_PIX (512*512)
#define KW 512
#define KC 2048
#define CAPW 4096
#define CAPC 4096
#define NUM_CLS 68
#define WORD_THR 0.5f
#define CHAR_THR 0.25f
#define IOU_THR 0.3f
#define NBLK 128
#define BS 512
#define GSZ (NBLK*BS)        // 65536 threads; exactly N_PIX/4 float4s
#define BASE16W 0x3F00u      // top16 of f32 in (0.5,1)  -> [0x3F00,0x3F80)
#define BASE16C 0x3E80u      // top16 of f32 in (0.25,1) -> [0x3E80,0x3F80)

struct SelState { u64 prefix; u32 kRem; u32 counter; u32 hist[256]; };

__device__ __forceinline__ u64 mk_key(u32 fb, u32 i){
  return (((u64)fb) << 32) | (u64)(0xFFFFFFFFu - i);
}

__global__ void k0_init(SelState* stW, SelState* stC, u32* bars){
  int t = threadIdx.x;
  if (t==0){ stW->prefix=0ull; stW->kRem=KW; stW->counter=0u; }
  if (t==1){ stC->prefix=0ull; stC->kRem=KC; stC->counter=0u; }
  if (t < 8) bars[t] = 0u;
  stW->hist[t]=0u; stC->hist[t]=0u;   // 256 threads
}

// 64-lane scan of 256-bin hist (descending): largest digit d with suffix-count >= kRem.
__device__ __forceinline__ void scan_wave(SelState* st, u32 base16, int lane){
  u32 h[4];
  #pragma unroll
  for (int q=0;q<4;q++)
    h[q] = __hip_atomic_load(&st->hist[lane*4+q], __ATOMIC_RELAXED, __HIP_MEMORY_SCOPE_AGENT);
  u32 lsum = h[0]+h[1]+h[2]+h[3];
  u32 v = lsum;
  #pragma unroll
  for (int off=1; off<64; off<<=1){
    u32 t2 = __shfl_down(v, off, 64);
    if (lane + off < 64) v += t2;
  }
  u32 above = v - lsum;                 // sum over lanes > lane
  u32 k = st->kRem;
  u32 sfx1 = h[3]+h[2]+h[1], sfx2 = h[3]+h[2], sfx3 = h[3];
  int best = -1;
  if      (above + sfx3 >= k) best = lane*4+3;
  else if (above + sfx2 >= k) best = lane*4+2;
  else if (above + sfx1 >= k) best = lane*4+1;
  else if (above + lsum >= k) best = lane*4+0;
  u64 m = __ballot(best >= 0);
  int d = 0;
  if (m != 0ull){
    int hi_lane = 63 - __clzll(m);
    d = __shfl(best, hi_lane, 64);
  }
  if (lane==0)
    __hip_atomic_store(&st->prefix, ((u64)(base16 + (u32)d)) << 48,
                       __ATOMIC_RELAXED, __HIP_MEMORY_SCOPE_AGENT);
}

// P0: one float4 image pass -> 256-bin top16 hist; last-done block scans.
__global__ __launch_bounds__(BS)
void k1_hist(const float* __restrict__ wfg, const float* __restrict__ cfg,
             SelState* stW, SelState* stC, u32* bars){
  __shared__ u32 hW[256], hC[256];
  __shared__ int isLast;
  const int tid = threadIdx.x;
  const int gtid = blockIdx.x*BS + tid;
  const int lane = tid & 63;
  if (tid < 256){ hW[tid]=0u; hC[tid]=0u; }
  __syncthreads();
  float4 wv4 = ((const float4*)wfg)[gtid];
  float4 cv4 = ((const float4*)cfg)[gtid];
  #pragma unroll
  for (int q=0;q<4;q++){
    float wf = q==0?wv4.x:(q==1?wv4.y:(q==2?wv4.z:wv4.w));
    float cf = q==0?cv4.x:(q==1?cv4.y:(q==2?cv4.z:cv4.w));
    bool wp = wf > WORD_THR;
    if (wp) atomicAdd(&hW[(__float_as_uint(wf)>>16) - BASE16W], 1u);
    if (wp && cf > CHAR_THR) atomicAdd(&hC[(__float_as_uint(cf)>>16) - BASE16C], 1u);
  }
  __syncthreads();
  if (tid < 256){
    if (hW[tid]) atomicAdd(&stW->hist[tid], hW[tid]);
    if (hC[tid]) atomicAdd(&stC->hist[tid], hC[tid]);
  }
  __syncthreads();
  if (tid==0){
    u32 p = __hip_atomic_fetch_add(&bars[0],1u,__ATOMIC_ACQ_REL,__HIP_MEMORY_SCOPE_AGENT);
    isLast = (p == NBLK-1);
  }
  __syncthreads();
  if (isLast && tid < 128){
    if (tid < 64) scan_wave(stW, BASE16W, lane);
    else          scan_wave(stC, BASE16C, lane);
  }
}

// P2: compact keys >= threshold (image re-read; L2/L3-warm)
__global__ __launch_bounds__(BS)
void k2_compact(const float* __restrict__ wfg, const float* __restrict__ cfg,
                SelState* stW, SelState* stC, u64* candW, u64* candC){
  const int gtid = blockIdx.x*BS + threadIdx.x;
  u64 tW = stW->prefix, tC = stC->prefix;
  float4 wv4 = ((const float4*)wfg)[gtid];
  float4 cv4 = ((const float4*)cfg)[gtid];
  #pragma unroll
  for (int q=0;q<4;q++){
    float wf = q==0?wv4.x:(q==1?wv4.y:(q==2?wv4.z:wv4.w));
    float cf = q==0?cv4.x:(q==1?cv4.y:(q==2?cv4.z:cv4.w));
    u32 i = 4u*(u32)gtid + (u32)q;
    bool wp = wf > WORD_THR;
    if (wp){
      u64 k = mk_key(__float_as_uint(wf), i);
      if (k >= tW){ u32 p = atomicAdd(&stW->counter,1u); if (p < CAPW) candW[p]=k; }
    }
    if (wp && cf > CHAR_THR){
      u64 k = mk_key(__float_as_uint(cf), i);
      if (k >= tC){ u32 p = atomicAdd(&stC->counter,1u); if (p < CAPC) candC[p]=k; }
    }
  }
}

// P3: row-group-per-block exact rank + immediate scatter + box construction
__global__ __launch_bounds__(BS)
void k3_rank_boxes(const u64* __restrict__ candW, const u64* __restrict__ candC,
                   SelState* stW, SelState* stC,
                   const float* __restrict__ wtblr, const float* __restrict__ worient,
                   const float* __restrict__ ctblr,
                   const int* p_sw, const int* p_sh, const int* p_ow, const int* p_oh,
                   u64* sortedW, u64* sortedC, float4* aabbW, float4* aabbC,
                   float* out_wb, float* out_cb){
  __shared__ u64 chunk[BS];
  const int tid = threadIdx.x;
  bool isW = (blockIdx.x < 8);
  int sg = isW ? blockIdx.x : blockIdx.x - 8;
  u32 C = isW ? stW->counter : stC->counter;
  u32 cap = isW ? CAPW : CAPC;
  if (C > cap) C = cap;
  int n = (int)((C + BS - 1) / BS);
  if (sg >= n) return;
  const u64* cand = isW ? candW : candC;
  int slot = sg*BS + tid;
  bool live = slot < (int)C;
  u64 my = live ? cand[slot] : 0ull;
  int rank = 0;
  for (int ch = 0; ch < n; ch++){
    __syncthreads();
    int ci = ch*BS + tid;
    chunk[tid] = (ci < (int)C) ? cand[ci] : 0ull;
    __syncthreads();
    if (live){
      const ulonglong2* cp = (const ulonglong2*)chunk;
      #pragma unroll 8
      for (int i2=0;i2<BS/2;i2++){ ulonglong2 v = cp[i2]; rank += (v.x > my) + (v.y > my); }
    }
  }
  int K = isW ? KW : KC;
  if (live && rank < K){
    (isW ? sortedW : sortedC)[rank] = my;
    u32 idx = 0xFFFFFFFFu - (u32)(my & 0xFFFFFFFFull);
    float score = __uint_as_float((u32)(my>>32));
    float swf = (float)(*p_sw) * 4.0f;    // WORD_STRIDE == CHAR_STRIDE == 4
    float shf = (float)(*p_sh) * 4.0f;
    float owm = (float)(*p_ow) - 1.0f, ohm = (float)(*p_oh) - 1.0f;
    const float* tblr = isW ? wtblr : ctblr;
    float tt2 = tblr[idx], bb = tblr[N_PIX+idx], ll = tblr[2*N_PIX+idx], rr = tblr[3*N_PIX+idx];
    float xf = (float)(idx & 511u), yf = (float)(idx >> 9);
    float c = 1.0f, sn = 0.0f;
    if (isW){ float o = worient[idx]; c = cosf(o); sn = sinf(o); }
    float x1 = swf*(xf - ll), x2 = swf*(xf + rr);
    float y1 = shf*(yf - tt2), y2 = shf*(yf + bb);
    float ax = swf*xf, ay = shf*yf;
    float cx[4] = {x1,x2,x2,x1};
    float cy[4] = {y1,y1,y2,y2};
    float rx[4], ry[4];
    #pragma unroll
    for (int q=0;q<4;q++){
      float dx = cx[q]-ax, dy = cy[q]-ay;
      rx[q] = ax + dx*c - dy*sn;
      ry[q] = ay + dx*sn + dy*c;
    }
    float minx = fminf(fminf(rx[0],rx[1]),fminf(rx[2],rx[3]));
    float maxx = fmaxf(fmaxf(rx[0],rx[1]),fmaxf(rx[2],rx[3]));
    float miny = fminf(fminf(ry[0],ry[1]),fminf(ry[2],ry[3]));
    float maxy = fmaxf(fmaxf(ry[0],ry[1]),fmaxf(ry[2],ry[3]));
    (isW ? aabbW : aabbC)[rank] = make_float4(minx,miny,maxx,maxy);
    float* ob = isW ? out_wb : out_cb;
    #pragma unroll
    for (int q=0;q<4;q++){
      ob[rank*9 + 2*q]   = fminf(fmaxf(rintf(rx[q]),0.0f), owm);
      ob[rank*9 + 2*q+1] = fminf(fmaxf(rintf(ry[q]),0.0f), ohm);
    }
    ob[rank*9+8] = score;
  }
}

template<int W>
__device__ __forceinline__ void sup_row(int j, int lane, const float4* __restrict__ aabb,
                                        u64* __restrict__ supT, u32* __restrict__ rm){
  float4 bj = aabb[j];
  float aj = fmaxf(bj.z-bj.x,0.0f)*fmaxf(bj.w-bj.y,0.0f);
  u32 m = 0;
  #pragma unroll 4
  for (int w=0; w<W; w++){
    int i = w*64 + lane;
    float4 bi = aabb[i];
    float ai = fmaxf(bi.z-bi.x,0.0f)*fmaxf(bi.w-bi.y,0.0f);
    float ix1=fmaxf(bi.x,bj.x), iy1=fmaxf(bi.y,bj.y);
    float ix2=fminf(bi.z,bj.z), iy2=fminf(bi.w,bj.w);
    float inter = fmaxf(ix2-ix1,0.0f)*fmaxf(iy2-iy1,0.0f);
    float iou = inter/(ai+aj-inter+1e-6f);
    bool bit = (iou > IOU_THR) && (i < j);
    u64 b = __ballot(bit);
    if (b){ if (lane==0) supT[(size_t)j*W + w] = b; m |= 1u << w; }
  }
  if (lane==0) rm[j] = m;
}

// P4: suppression matrix + class gather
__global__ __launch_bounds__(BS)
void k4_sup_gather(const float4* __restrict__ aabbW, const float4* __restrict__ aabbC,
                   u64* supTW, u64* supTC, u32* rmW, u32* rmC,
                   const u64* __restrict__ sortedC, const float* __restrict__ ccls,
                   float* __restrict__ out_cs){
  const int tid = threadIdx.x;
  const int gtid = blockIdx.x*BS + tid;
  const int lane = tid & 63;
  int gw = gtid >> 6;                        // 1024 waves, 2-3 rows each
  for (int row = gw; row < KW+KC; row += GSZ/64){
    if (row < KW) sup_row<KW/64>(row, lane, aabbW, supTW, rmW);
    else          sup_row<KC/64>(row-KW, lane, aabbC, supTC, rmC);
  }
  for (int t = gtid; t < KC*NUM_CLS; t += GSZ){
    int k = t / NUM_CLS;
    int c = t - k*NUM_CLS;
    u32 idx = 0xFFFFFFFFu - (u32)(sortedC[k] & 0xFFFFFFFFull);
    out_cs[t] = ccls[(size_t)c*N_PIX + idx];
  }
}

// P5: NMS Jacobi fixpoint (unique fixed point == greedy NMS result)
template<int K, int W>
__device__ void nms_body(u64* kw, int* changed,
                         const u64* __restrict__ supT, const u32* __restrict__ rm,
                         const u64* __restrict__ sorted, float* __restrict__ keep){
  const int tid = threadIdx.x;
  const int lane = tid & 63, wv = tid >> 6;
  constexpr int NB = (K + BS - 1)/BS;
  if (tid < W) kw[tid] = ~0ull;
  __syncthreads();
  for(;;){
    if (tid==0) *changed = 0;
    __syncthreads();
    bool nb[NB];
    #pragma unroll
    for (int q=0;q<NB;q++){
      int j = q*BS + tid;
      bool ok = (j < K);
      u64 su = 0ull;
      if (ok){
        u32 m = rm[j];
        while (m){ int w = __ffs(m)-1; m &= m-1u; su |= supT[(size_t)j*W + w] & kw[w]; }
      }
      nb[q] = ok && (su == 0ull);
    }
    __syncthreads();
    #pragma unroll
    for (int q=0;q<NB;q++){
      int wi = q*(BS/64) + wv;
      u64 b = __ballot(nb[q]);
      if (lane==0 && wi < W){
        if (b != kw[wi]){ kw[wi] = b; *changed = 1; }
      }
    }
    __syncthreads();
    int ch = *changed;
    __syncthreads();
    if (!ch) break;
  }
  #pragma unroll
  for (int q=0;q<NB;q++){
    int j = q*BS + tid;
    if (j < K){
      u64 key = sorted[j];
      bool pos = ((u32)(key>>32)) != 0u;
      bool kp = (((kw[j>>6] >> (j&63)) & 1ull) != 0ull) && pos;
      keep[j] = kp ? 1.0f : 0.0f;
    }
  }
}

__global__ __launch_bounds__(BS)
void k5_nms(const u64* supTW, const u32* rmW, const u64* sortedW, float* keepW,
            const u64* supTC, const u32* rmC, const u64* sortedC, float* keepC){
  __shared__ u64 kw[KC/64];
  __shared__ int changed;
  if (blockIdx.x == 0) nms_body<KW, KW/64>(kw, &changed, supTW, rmW, sortedW, keepW);
  else                 nms_body<KC, KC/64>(kw, &changed, supTC, rmC, sortedC, keepC);
}

extern "C" void kernel_launch(void* const* d_in, const int* in_sizes, int n_in,
                              void* d_out, int out_size, void* d_ws, size_t ws_size,
                              hipStream_t stream) {
  const float* wfg     = (const float*)d_in[0];
  const float* wtblr   = (const float*)d_in[1];
  const float* worient = (const float*)d_in[2];
  const float* cfg     = (const float*)d_in[3];
  const float* ctblr   = (const float*)d_in[4];
  const float* ccls    = (const float*)d_in[5];
  const int* p_sw = (const int*)d_in[6];
  const int* p_sh = (const int*)d_in[7];
  const int* p_ow = (const int*)d_in[8];
  const int* p_oh = (const int*)d_in[9];

  // ws layout (phase-overlayed; all accesses < 631824 B)
  char* ws = (char*)d_ws;
  u64* candW   = (u64*)(ws + 0);        // dies after k3; then supTW
  u64* candC   = (u64*)(ws + 32768);    // dies after k3; then supTC
  u64* supTW   = (u64*)(ws + 0);
  u64* supTC   = (u64*)(ws + 32768);    // spans to 557056
  u64* sortedW = (u64*)(ws + 557056);
  u64* sortedC = (u64*)(ws + 561152);
  float4* aabbW= (float4*)(ws + 577536);
  float4* aabbC= (float4*)(ws + 585728);
  u32* rmW     = (u32*)(ws + 618496);
  u32* rmC     = (u32*)(ws + 620544);
  SelState* stW= (SelState*)(ws + 628736);
  u32* bars    = (u32*)(ws + 630016);
  SelState* stC= (SelState*)(ws + 630784);

  float* out = (float*)d_out;
  float* out_cb = out;                          // char bboxes 2048*9
  float* out_cs = out + KC*9;                   // char scores 2048*68
  float* out_wb = out + KC*9 + KC*NUM_CLS;      // word bboxes 512*9
  float* out_wk = out_wb + KW*9;                // wkeep 512
  float* out_ck = out_wk + KW;                  // ckeep 2048

  k0_init<<<1, 256, 0, stream>>>(stW, stC, bars);
  k1_hist<<<NBLK, BS, 0, stream>>>(wfg, cfg, stW, stC, bars);
  k2_compact<<<NBLK, BS, 0, stream>>>(wfg, cfg, stW, stC, candW, candC);
  k3_rank_boxes<<<16, BS, 0, stream>>>(candW, candC, stW, stC, wtblr, worient, ctblr,
                                       p_sw, p_sh, p_ow, p_oh,
                                       sortedW, sortedC, aabbW, aabbC, out_wb, out_cb);
  k4_sup_gather<<<NBLK, BS, 0, stream>>>(aabbW, aabbC, supTW, supTC, rmW, rmC,
                                         sortedC, ccls, out_cs);
  k5_nms<<<2, BS, 0, stream>>>(supTW, rmW, sortedW, out_wk, supTC, rmC, sortedC, out_ck);
}